// Round 6
// baseline (108.695 us; speedup 1.0000x reference)
//
#include <hip/hip_runtime.h>

// ---------------- constants / ws layout (floats) ----------------
#define TT_ISTRIDE 672            // Tt per-i stride = 8 r * 84 padded j
#define TT_ELEMS (4 * 81 * 672)   // 217728
#define WS_H   217728             // h_ws: [4 a][8192 b][36]   (1179648 floats)
#define WS_RIS 1397376            // risP: [2 ihalf][4 a][8192 b][8] (524288 floats)
#define RIS_IHALF_STRIDE 262144

// Transpose T[a][q0][q1][q2][q3][r] -> Tt[a][i][r][84]; j split in three 28-wide
// 16B-aligned thirds: col = jt*28 + (j - jt*27), slot 27 of each third = 0 pad.
__global__ void t_transpose(const float* __restrict__ T, float* __restrict__ Tt) {
    int idx = blockIdx.x * 256 + threadIdx.x;
    if (idx >= TT_ELEMS) return;
    int col  = idx % 84;
    int t1   = idx / 84;
    int r    = t1 & 7;
    int rest = t1 / 8;  // a*81 + i
    int jt   = col / 28;
    int kk   = col - jt * 28;
    Tt[idx] = (kk < 27) ? T[rest * 648 + (jt * 27 + kk) * 8 + r] : 0.0f;
}

#define GLL(gsrc, ldst) __builtin_amdgcn_global_load_lds( \
    (const __attribute__((address_space(1))) void*)(gsrc), \
    (__attribute__((address_space(3))) void*)(ldst), 16, 0, 0)

#define KEEP(x) asm volatile("" : "+v"(x))

// ---------------- K1: phase X ----------------
// x[b,c,a,r] = nh[b,c,:].U[c,a,:,r] + bi[c,a,r]; write augmented h rows to h_ws.
// Block: 128 batches x 1 a; 512 thr: thread=(b=t&127, rp=t>>7) computes r={rp,rp+4}.
// nh tiles staged coalesced per (c, h-quarter). Grid 256: a=bid>>6 so the 4 a-blocks
// of a batch-group land on one XCD (bid%8 equal) -> nh L2-shared.
__global__ __launch_bounds__(512, 4) void k1_phasex(
    const float* __restrict__ nh, const float* __restrict__ U,
    const float* __restrict__ bi, float* __restrict__ h_ws) {
    __shared__ float nh_s[128 * 68];   // [b][64h], pad 68
    __shared__ float u_s[8 * 68];      // [r][64h]
    const int t  = threadIdx.x;
    const int a  = blockIdx.x >> 6;
    const int b0 = (blockIdx.x & 63) << 7;
    const int b  = t & 127;
    const int rp = t >> 7;

    #pragma unroll 1
    for (int c = 0; c < 4; ++c) {
        float acc0 = 0.f, acc1 = 0.f;
        #pragma unroll 1
        for (int hq = 0; hq < 4; ++hq) {
            __syncthreads();   // prev-stage reads done before overwrite
            #pragma unroll
            for (int k = 0; k < 4; ++k) {
                int idx = t + (k << 9);
                int row = idx >> 4, col = (idx & 15) << 2;
                *(float4*)(nh_s + row * 68 + col) =
                    *(const float4*)(nh + (size_t)(b0 + row) * 1024 + (c << 8) + (hq << 6) + col);
            }
            u_s[(t & 7) * 68 + (t >> 3)] =
                U[(((c << 2) + a) << 11) + (((hq << 6) + (t >> 3)) << 3) + (t & 7)];
            __syncthreads();
            const float* nhp = nh_s + b * 68;
            const float* u0p = u_s + rp * 68;
            const float* u1p = u_s + (rp + 4) * 68;
            #pragma unroll
            for (int hh = 0; hh < 64; hh += 4) {
                float4 v  = *(const float4*)(nhp + hh);
                float4 ua = *(const float4*)(u0p + hh);
                float4 ub = *(const float4*)(u1p + hh);
                acc0 = fmaf(v.x, ua.x, acc0); acc0 = fmaf(v.y, ua.y, acc0);
                acc0 = fmaf(v.z, ua.z, acc0); acc0 = fmaf(v.w, ua.w, acc0);
                acc1 = fmaf(v.x, ub.x, acc1); acc1 = fmaf(v.y, ub.y, acc1);
                acc1 = fmaf(v.z, ub.z, acc1); acc1 = fmaf(v.w, ub.w, acc1);
            }
        }
        acc0 += bi[(((c << 2) + a) << 3) + rp];
        acc1 += bi[(((c << 2) + a) << 3) + rp + 4];
        size_t hb = ((size_t)a * 8192 + b0 + b) * 36 + c * 9;
        h_ws[hb + rp]     = acc0;
        h_ws[hb + rp + 4] = acc1;
        if (rp == 0) h_ws[hb + 8] = 1.0f;
    }
}

// ---------------- K2: chain contraction ----------------
// Block: 256 batches x 1 a x 1 i-half (q0 in [0,4) or [4,9)); 512 thr = 8 waves.
// Wave w: r=w; lane owns 4 batches (lane+64k). T chunk (one q0, 9 i) = 24.2 KB
// double-buffered via global_load_lds + vmcnt(3). h2/h3 pinned in VGPRs (static
// indices only); h0/h1 re-read from LDS (runtime q1 index would scratch-spill).
__global__ __launch_bounds__(512, 2) void k2_chain(
    const float* __restrict__ Tt, const float* __restrict__ h_ws,
    float* __restrict__ risP) {
    __shared__ float tc[2][9 * 672];   // 48.4 KB
    __shared__ float h_s[36 * 260];    // 37.4 KB, [q][batch] lane-stride-1

    const int t    = threadIdx.x;
    const int lane = t & 63;
    const int widr = t >> 6;
    const int ihalf = blockIdx.x >> 7;
    const int a     = (blockIdx.x >> 5) & 3;
    const int b0    = (blockIdx.x & 31) << 8;
    const int q0base = ihalf ? 4 : 0;
    const int NC     = ihalf ? 5 : 4;

    const float* Tw = Tt + (size_t)a * 54432 + (size_t)q0base * 6048;

    // prologue: stage chunk 0 (overlaps with h staging below)
    {
        const float* s = Tw;
        float* d = tc[0];
        GLL(s + 4 * t, d + 4 * t);
        GLL(s + 4 * (512 + t), d + 4 * (512 + t));
        if (t < 488) GLL(s + 4 * (1024 + t), d + 4 * (1024 + t));
    }
    // stage h for 256 batches: h_ws[a][b0+b][36] -> h_s[q][b]
    for (int idx = t; idx < 2304; idx += 512) {
        int bb = idx / 9, j = idx % 9;
        float4 v = *(const float4*)(h_ws + ((size_t)a * 8192 + b0 + bb) * 36 + j * 4);
        h_s[(4 * j + 0) * 260 + bb] = v.x;
        h_s[(4 * j + 1) * 260 + bb] = v.y;
        h_s[(4 * j + 2) * 260 + bb] = v.z;
        h_s[(4 * j + 3) * 260 + bb] = v.w;
    }
    __syncthreads();   // drains prologue DMA + h_s writes

    // h2,h3 into registers, pinned (36+36 = 72 VGPR)
    float h2v[4][9], h3v[4][9];
    #pragma unroll
    for (int k = 0; k < 4; ++k) {
        #pragma unroll
        for (int q = 0; q < 9; ++q) {
            h2v[k][q] = h_s[(18 + q) * 260 + lane + 64 * k];
            h3v[k][q] = h_s[(27 + q) * 260 + lane + 64 * k];
        }
    }
    #pragma unroll
    for (int k = 0; k < 4; ++k) {
        #pragma unroll
        for (int q = 0; q < 9; ++q) { KEEP(h2v[k][q]); KEEP(h3v[k][q]); }
    }

    float A0 = 0.f, A1 = 0.f, A2 = 0.f, A3 = 0.f;

    #pragma unroll 1
    for (int c = 0; c < NC; ++c) {
        if (c < NC - 1) {
            const float* s = Tw + (size_t)(c + 1) * 6048;
            float* d = tc[(c + 1) & 1];
            GLL(s + 4 * t, d + 4 * t);
            GLL(s + 4 * (512 + t), d + 4 * (512 + t));
            if (t < 488) GLL(s + 4 * (1024 + t), d + 4 * (1024 + t));
            asm volatile("s_waitcnt vmcnt(3)" ::: "memory");   // chunk c landed
        } else {
            asm volatile("s_waitcnt vmcnt(0)" ::: "memory");
        }
        __builtin_amdgcn_s_barrier();
        asm volatile("" ::: "memory");

        const float* tb = tc[c & 1] + widr * 84;   // r = widr
        float h0c[4];
        #pragma unroll
        for (int k = 0; k < 4; ++k)
            h0c[k] = h_s[(q0base + c) * 260 + lane + 64 * k];

        #pragma unroll 1
        for (int q1 = 0; q1 < 9; ++q1) {
            float h1q[4];
            #pragma unroll
            for (int k = 0; k < 4; ++k)
                h1q[k] = h_s[(9 + q1) * 260 + lane + 64 * k];
            const float* tp = tb + q1 * TT_ISTRIDE;
            float dd[4] = {0.f, 0.f, 0.f, 0.f};
            #pragma unroll
            for (int jt = 0; jt < 3; ++jt) {
                float s[28];
                #pragma unroll
                for (int m = 0; m < 7; ++m)
                    *(float4*)(s + 4 * m) = *(const float4*)(tp + jt * 28 + 4 * m);
                #pragma unroll
                for (int k = 0; k < 4; ++k) {
                    float e0 = 0.f, e1 = 0.f, e2 = 0.f;
                    #pragma unroll
                    for (int m = 0; m < 9; ++m) {
                        e0 = fmaf(s[m],      h3v[k][m], e0);
                        e1 = fmaf(s[9 + m],  h3v[k][m], e1);
                        e2 = fmaf(s[18 + m], h3v[k][m], e2);
                    }
                    dd[k] = fmaf(h2v[k][3 * jt], e0, fmaf(h2v[k][3 * jt + 1], e1,
                            fmaf(h2v[k][3 * jt + 2], e2, dd[k])));
                }
            }
            A0 = fmaf(h0c[0] * h1q[0], dd[0], A0);
            A1 = fmaf(h0c[1] * h1q[1], dd[1], A1);
            A2 = fmaf(h0c[2] * h1q[2], dd[2], A2);
            A3 = fmaf(h0c[3] * h1q[3], dd[3], A3);
        }
        asm volatile("" ::: "memory");
        __builtin_amdgcn_s_barrier();   // buffer reuse safe
    }

    size_t rb = (size_t)ihalf * RIS_IHALF_STRIDE + ((size_t)a * 8192 + b0) * 8 + widr;
    risP[rb + (size_t)(lane)       * 8] = A0;
    risP[rb + (size_t)(lane + 64)  * 8] = A1;
    risP[rb + (size_t)(lane + 128) * 8] = A2;
    risP[rb + (size_t)(lane + 192) * 8] = A3;
}

// ---------------- K3: reduce partials + output projection ----------------
// Block: 16 batches, 256 thr; thread t: a = t>>6, 4 columns; coalesced f4 out.
__global__ __launch_bounds__(256, 8) void k3_out(
    const float* __restrict__ risP, const float* __restrict__ Uo,
    const float* __restrict__ bo, float* __restrict__ out) {
    __shared__ float uo_s[8192];
    __shared__ float bo_s[1024];
    __shared__ float ris_s[16 * 32];   // [b][a*8+r]
    const int t  = threadIdx.x;
    const int b0 = blockIdx.x << 4;
    for (int idx = t; idx < 8192; idx += 256) uo_s[idx] = Uo[idx];
    for (int idx = t; idx < 1024; idx += 256) bo_s[idx] = bo[idx];
    for (int idx = t; idx < 512; idx += 256) {
        int bb = idx >> 5, rem = idx & 31, aa = rem >> 3, rr = rem & 7;
        size_t ro = ((size_t)aa * 8192 + b0 + bb) * 8 + rr;
        ris_s[bb * 32 + rem] = risP[ro] + risP[RIS_IHALF_STRIDE + ro];
    }
    __syncthreads();
    const int a  = t >> 6;
    const int c4 = (t & 63) << 2;
    float4 u[8];
    #pragma unroll
    for (int r = 0; r < 8; ++r)
        u[r] = *(const float4*)(uo_s + (a << 11) + (r << 8) + c4);
    const float4 b4 = *(const float4*)(bo_s + (a << 8) + c4);
    #pragma unroll 4
    for (int bb = 0; bb < 16; ++bb) {
        const float* rp = ris_s + bb * 32 + a * 8;
        float4 v = b4;
        #pragma unroll
        for (int r = 0; r < 8; ++r) {
            float w = rp[r];
            v.x = fmaf(w, u[r].x, v.x); v.y = fmaf(w, u[r].y, v.y);
            v.z = fmaf(w, u[r].z, v.z); v.w = fmaf(w, u[r].w, v.w);
        }
        *(float4*)(out + (size_t)(b0 + bb) * 1024 + (a << 8) + c4) = v;
    }
}

extern "C" void kernel_launch(void* const* d_in, const int* in_sizes, int n_in,
                              void* d_out, int out_size, void* d_ws, size_t ws_size,
                              hipStream_t stream) {
    (void)in_sizes; (void)n_in; (void)out_size; (void)ws_size;
    const float* nh = (const float*)d_in[0];
    const float* U  = (const float*)d_in[1];
    const float* bi = (const float*)d_in[2];
    const float* Uo = (const float*)d_in[3];
    const float* bo = (const float*)d_in[4];
    const float* T  = (const float*)d_in[5];
    float* outp = (float*)d_out;
    float* ws   = (float*)d_ws;   // needs 1,921,664 floats = 7.69 MB

    t_transpose<<<(TT_ELEMS + 255) / 256, 256, 0, stream>>>(T, ws);
    k1_phasex<<<256, 512, 0, stream>>>(nh, U, bi, ws + WS_H);
    k2_chain<<<256, 512, 0, stream>>>(ws, ws + WS_H, ws + WS_RIS);
    k3_out<<<512, 256, 0, stream>>>(ws + WS_RIS, Uo, bo, outp);
}